// Round 1
// baseline (360.832 us; speedup 1.0000x reference)
//
#include <hip/hip_runtime.h>
#include <hip/hip_fp16.h>

// GRU encoder: B=64, T=24, N=184, HID=128, input dim 2 (prev fc output, pm_t).
// Strategy: 246 blocks x 256 threads; each block owns 48 (b,n) rows for all 24
// steps. Per step: gh = h @ W_hh^T via v_mfma_f32_16x16x32_f16 (W_hh cached in
// registers as f16 fragments), register-local gate math, h kept fp32 in LDS
// (f16 copy only as MFMA A operand), fc reduction via shfl butterfly.

#define B_   64
#define T_   24
#define N_   184
#define H_   128
#define BN   (B_ * N_)            // 11776
#define TN   (T_ * N_)            // 4416
#define HSZ  (B_ * T_ * N_ * H_)  // 36175872
#define MROWS 48
#define NBLK  246                 // ceil(11776 / 48)
#define S16   136                 // f16 h row stride (halves); 272B rows, 16B aligned
#define S32   132                 // fp32 h row stride (floats); breaks bank conflicts

typedef _Float16 v8h __attribute__((ext_vector_type(8)));
typedef float    v4f __attribute__((ext_vector_type(4)));

static __device__ __forceinline__ float fast_rcp(float x) {
#if __has_builtin(__builtin_amdgcn_rcpf)
    return __builtin_amdgcn_rcpf(x);
#else
    return 1.0f / x;
#endif
}
static __device__ __forceinline__ float sigm_f(float x) {
    // 1/(1+e^-x); saturates correctly at +-inf via rcp(inf)=0
    return fast_rcp(1.0f + __expf(-x));
}
static __device__ __forceinline__ float tanh_f(float x) {
    // tanh(x) = 1 - 2/(e^{2x}+1)
    return 1.0f - 2.0f * fast_rcp(1.0f + __expf(2.0f * x));
}

__global__ __launch_bounds__(256, 1)
void gru_encoder_kernel(const float* __restrict__ pm,    // [B,T,N]
                        const float* __restrict__ Wih,   // [384,2]
                        const float* __restrict__ Whh,   // [384,128]
                        const float* __restrict__ bih,   // [384]
                        const float* __restrict__ bhh,   // [384]
                        const float* __restrict__ fcw,   // [128]
                        const float* __restrict__ fcb,   // [1]
                        float* __restrict__ out)         // [HSZ] H + [BN] xn
{
    __shared__ _Float16 hf[MROWS * S16];   // f16 copy of h (MFMA A operand)
    __shared__ float    h32[MROWS * S32];  // fp32 master h
    __shared__ float    xlds[MROWS];       // x_prev per row
    __shared__ float    xpart[4 * MROWS];  // per-wave fc partials

    const int tid  = threadIdx.x;
    const int w    = tid >> 6;   // wave 0..3
    const int lane = tid & 63;
    const int u    = lane & 15;  // MFMA col / A-row selector
    const int q    = lane >> 4;  // MFMA quad

    // ---- zero h state ----
    for (int idx = tid; idx < MROWS * S16; idx += 256) hf[idx] = (_Float16)0.0f;
    for (int idx = tid; idx < MROWS * S32; idx += 256) h32[idx] = 0.0f;
    if (tid < MROWS) xlds[tid] = 0.0f;

    // ---- load W_hh B-fragments into registers (once) ----
    // B[k][n] = Whh[n][k]; lane holds B[ks*32 + q*8 + j][g*128 + (2w+p)*16 + u]
    v8h bfr[3][2][4];
#pragma unroll
    for (int g = 0; g < 3; ++g)
#pragma unroll
        for (int p = 0; p < 2; ++p) {
            const int n = g * 128 + (2 * w + p) * 16 + u;
#pragma unroll
            for (int ks = 0; ks < 4; ++ks) {
                const float* src = Whh + n * 128 + ks * 32 + q * 8;
                v8h hb;
#pragma unroll
                for (int j = 0; j < 8; ++j) hb[j] = (_Float16)src[j];
                bfr[g][p][ks] = hb;
            }
        }

    // ---- per-lane constants ----
    float wih0[3][2], wih1[3][2], bihr[3][2], bhhr[3][2], fcwr[2];
#pragma unroll
    for (int g = 0; g < 3; ++g)
#pragma unroll
        for (int p = 0; p < 2; ++p) {
            const int i = (2 * w + p) * 16 + u;
            const int c = g * 128 + i;
            wih0[g][p] = Wih[c * 2 + 0];
            wih1[g][p] = Wih[c * 2 + 1];
            bihr[g][p] = bih[c];
            bhhr[g][p] = bhh[c];
        }
#pragma unroll
    for (int p = 0; p < 2; ++p) fcwr[p] = fcw[(2 * w + p) * 16 + u];
    const float fcbv = fcb[0];

    // ---- per-lane row bases: obase = b*T*N + n for rows (mt, reg) ----
    int obase[3][4];
#pragma unroll
    for (int mt = 0; mt < 3; ++mt)
#pragma unroll
        for (int reg = 0; reg < 4; ++reg) {
            const int lr = mt * 16 + q * 4 + reg;
            const int g  = blockIdx.x * MROWS + lr;
            if (g < BN) {
                const int b = g / N_;
                const int n = g - b * N_;
                obase[mt][reg] = b * TN + n;
            } else {
                obase[mt][reg] = -1;
            }
        }

    __syncthreads();

    for (int t = 0; t < T_; ++t) {
        // ================= phase 1: gh = h @ Whh^T (MFMA) =================
        v4f acc[3][3][2];
#pragma unroll
        for (int mt = 0; mt < 3; ++mt)
#pragma unroll
            for (int g = 0; g < 3; ++g)
#pragma unroll
                for (int p = 0; p < 2; ++p) acc[mt][g][p] = (v4f){0.f, 0.f, 0.f, 0.f};

#pragma unroll
        for (int ks = 0; ks < 4; ++ks) {
            v8h afr[3];
#pragma unroll
            for (int mt = 0; mt < 3; ++mt) {
                const _Float16* ap = &hf[(mt * 16 + u) * S16 + ks * 32 + q * 8];
                afr[mt] = *(const v8h*)ap;  // ds_read_b128
            }
#pragma unroll
            for (int mt = 0; mt < 3; ++mt)
#pragma unroll
                for (int g = 0; g < 3; ++g)
#pragma unroll
                    for (int p = 0; p < 2; ++p)
                        acc[mt][g][p] = __builtin_amdgcn_mfma_f32_16x16x32_f16(
                            afr[mt], bfr[g][p][ks], acc[mt][g][p], 0, 0, 0);
        }
        __syncthreads();  // all A reads done before h is overwritten

        // ================= phase 2: gates + h update + fc partials ========
        const int tN = t * N_;
#pragma unroll
        for (int mt = 0; mt < 3; ++mt) {
#pragma unroll
            for (int reg = 0; reg < 4; ++reg) {
                const int lr   = mt * 16 + q * 4 + reg;
                const int ob   = obase[mt][reg];
                const bool vrow = (ob >= 0);
                const float xp  = xlds[lr];
                const float pmv = vrow ? pm[ob + tN] : 0.0f;
                float xsum = 0.0f;
#pragma unroll
                for (int p = 0; p < 2; ++p) {
                    const int i = (2 * w + p) * 16 + u;
                    const float hr = acc[mt][0][p][reg] + bhhr[0][p];
                    const float hz = acc[mt][1][p][reg] + bhhr[1][p];
                    const float hn = acc[mt][2][p][reg] + bhhr[2][p];
                    const float gir = xp * wih0[0][p] + pmv * wih1[0][p] + bihr[0][p];
                    const float giz = xp * wih0[1][p] + pmv * wih1[1][p] + bihr[1][p];
                    const float gin = xp * wih0[2][p] + pmv * wih1[2][p] + bihr[2][p];
                    const float r  = sigm_f(gir + hr);
                    const float z  = sigm_f(giz + hz);
                    const float nt = tanh_f(gin + r * hn);
                    const float hold = h32[lr * S32 + i];
                    const float hnew = (1.0f - z) * nt + z * hold;
                    if (vrow) {
                        h32[lr * S32 + i] = hnew;
                        hf[lr * S16 + i]  = (_Float16)hnew;
                        __builtin_nontemporal_store(hnew, &out[(ob + tN) * H_ + i]);
                        xsum += hnew * fcwr[p];
                    }
                }
                // reduce over the 16 u-lanes of this quad
                xsum += __shfl_xor(xsum, 1, 64);
                xsum += __shfl_xor(xsum, 2, 64);
                xsum += __shfl_xor(xsum, 4, 64);
                xsum += __shfl_xor(xsum, 8, 64);
                if (u == 0) xpart[w * MROWS + lr] = xsum;
            }
        }
        __syncthreads();  // xpart ready; h writes done before next MFMA reads

        // ================= phase 3: finish x_new =========================
        if (tid < MROWS) {
            const float x = xpart[tid] + xpart[MROWS + tid] + xpart[2 * MROWS + tid] +
                            xpart[3 * MROWS + tid] + fcbv;
            xlds[tid] = x;
            if (t == T_ - 1) {
                const int g = blockIdx.x * MROWS + tid;
                if (g < BN) out[HSZ + g] = x;
            }
        }
        // no barrier needed: next phase-1 doesn't touch xlds/xpart, and the
        // phase-1-end barrier orders xlds writes before the next gate phase.
    }
}

extern "C" void kernel_launch(void* const* d_in, const int* in_sizes, int n_in,
                              void* d_out, int out_size, void* d_ws, size_t ws_size,
                              hipStream_t stream) {
    const float* pm  = (const float*)d_in[0];  // [B,T,N,1]
    const float* Wih = (const float*)d_in[1];  // [384,2]
    const float* Whh = (const float*)d_in[2];  // [384,128]
    const float* bih = (const float*)d_in[3];  // [384]
    const float* bhh = (const float*)d_in[4];  // [384]
    const float* fcw = (const float*)d_in[5];  // [1,128]
    const float* fcb = (const float*)d_in[6];  // [1]
    float* out = (float*)d_out;

    gru_encoder_kernel<<<dim3(NBLK), dim3(256), 0, stream>>>(
        pm, Wih, Whh, bih, bhh, fcw, fcb, out);
}

// Round 2
// 227.032 us; speedup vs baseline: 1.5893x; 1.5893x over previous
//
#include <hip/hip_runtime.h>
#include <hip/hip_fp16.h>

// GRU encoder: B=64, T=24, N=184, HID=128, input dim 2 (prev fc output, pm_t).
// R2: latency-bound fix. 736 blocks x 256 threads, 16 rows/block (exact, no
// tail), __launch_bounds__(256,2) so 2 blocks co-reside per CU. h state lives
// in registers (MFMA C-fragment layout); f16 copy in LDS is the only A
// operand. pm preloaded to LDS. Normal (L2-merged) output stores.

#define B_   64
#define T_   24
#define N_   184
#define H_   128
#define BN   (B_ * N_)            // 11776
#define TN   (T_ * N_)            // 4416
#define HSZ  (B_ * T_ * N_ * H_)  // 36175872
#define MROWS 16
#define NBLK  (BN / MROWS)        // 736, exact
#define S16   136                 // f16 h row stride in halves (272B, 16B-aligned)

typedef _Float16 v8h __attribute__((ext_vector_type(8)));
typedef float    v4f __attribute__((ext_vector_type(4)));

static __device__ __forceinline__ float fast_rcp(float x) {
#if __has_builtin(__builtin_amdgcn_rcpf)
    return __builtin_amdgcn_rcpf(x);
#else
    return 1.0f / x;
#endif
}
static __device__ __forceinline__ float sigm_f(float x) {
    return fast_rcp(1.0f + __expf(-x));
}
static __device__ __forceinline__ float tanh_f(float x) {
    return 1.0f - 2.0f * fast_rcp(1.0f + __expf(2.0f * x));
}

__global__ __launch_bounds__(256, 2)
void gru_encoder_kernel(const float* __restrict__ pm,    // [B,T,N]
                        const float* __restrict__ Wih,   // [384,2]
                        const float* __restrict__ Whh,   // [384,128]
                        const float* __restrict__ bih,   // [384]
                        const float* __restrict__ bhh,   // [384]
                        const float* __restrict__ fcw,   // [128]
                        const float* __restrict__ fcb,   // [1]
                        float* __restrict__ out)         // [HSZ] H + [BN] xn
{
    __shared__ _Float16 hf[MROWS * S16];   // f16 h copy (MFMA A operand)
    __shared__ float    pml[T_ * MROWS];   // preloaded pm [t][row]
    __shared__ float    xlds[MROWS];       // x_prev per row
    __shared__ float    xpart[4 * MROWS];  // per-wave fc partials

    const int tid  = threadIdx.x;
    const int w    = tid >> 6;   // wave 0..3
    const int lane = tid & 63;
    const int u    = lane & 15;  // MFMA col / A-row selector
    const int q    = lane >> 4;  // MFMA quad

    // ---- zero h f16 copy, xlds ----
    for (int idx = tid; idx < MROWS * S16; idx += 256) hf[idx] = (_Float16)0.0f;
    if (tid < MROWS) xlds[tid] = 0.0f;

    // ---- preload pm for this block's 16 rows, all 24 steps ----
    for (int idx = tid; idx < T_ * MROWS; idx += 256) {
        const int row = idx & (MROWS - 1);
        const int t   = idx >> 4;
        const int g   = blockIdx.x * MROWS + row;
        const int b   = g / N_;
        const int n   = g - b * N_;
        pml[t * MROWS + row] = pm[b * TN + t * N_ + n];
    }

    // ---- W_hh B-fragments into registers (once) ----
    // B[k][n] = Whh[n][k]; lane holds B[ks*32 + q*8 + j][g*128 + (2w+p)*16 + u]
    v8h bfr[3][2][4];
#pragma unroll
    for (int g = 0; g < 3; ++g)
#pragma unroll
        for (int p = 0; p < 2; ++p) {
            const int n = g * 128 + (2 * w + p) * 16 + u;
#pragma unroll
            for (int ks = 0; ks < 4; ++ks) {
                const float* src = Whh + n * 128 + ks * 32 + q * 8;
                v8h hb;
#pragma unroll
                for (int j = 0; j < 8; ++j) hb[j] = (_Float16)src[j];
                bfr[g][p][ks] = hb;
            }
        }

    // ---- per-lane constants (biases for r,z merged) ----
    float w0[3][2], w1[3][2], brz0[2], brz1[2], bin_[2], bhn_[2], fcwr[2];
#pragma unroll
    for (int p = 0; p < 2; ++p) {
        const int i = (2 * w + p) * 16 + u;
        w0[0][p] = Wih[(0 * 128 + i) * 2 + 0];  w1[0][p] = Wih[(0 * 128 + i) * 2 + 1];
        w0[1][p] = Wih[(1 * 128 + i) * 2 + 0];  w1[1][p] = Wih[(1 * 128 + i) * 2 + 1];
        w0[2][p] = Wih[(2 * 128 + i) * 2 + 0];  w1[2][p] = Wih[(2 * 128 + i) * 2 + 1];
        brz0[p] = bih[0 * 128 + i] + bhh[0 * 128 + i];
        brz1[p] = bih[1 * 128 + i] + bhh[1 * 128 + i];
        bin_[p] = bih[2 * 128 + i];
        bhn_[p] = bhh[2 * 128 + i];
        fcwr[p] = fcw[i];
    }
    const float fcbv = fcb[0];

    // ---- per-lane row output bases: obase = b*T*N + n for row q*4+reg ----
    int obase[4];
#pragma unroll
    for (int reg = 0; reg < 4; ++reg) {
        const int g = blockIdx.x * MROWS + q * 4 + reg;
        const int b = g / N_;
        obase[reg] = b * TN + (g - b * N_);
    }

    // ---- h state in registers (MFMA C-fragment layout) ----
    v4f hreg[2];
    hreg[0] = (v4f){0.f, 0.f, 0.f, 0.f};
    hreg[1] = (v4f){0.f, 0.f, 0.f, 0.f};

    __syncthreads();

    for (int t = 0; t < T_; ++t) {
        // ============ phase 1: gh = h @ Whh^T (MFMA) ============
        v4f acc[3][2];
#pragma unroll
        for (int g = 0; g < 3; ++g)
#pragma unroll
            for (int p = 0; p < 2; ++p) acc[g][p] = (v4f){0.f, 0.f, 0.f, 0.f};

#pragma unroll
        for (int ks = 0; ks < 4; ++ks) {
            const v8h afr = *(const v8h*)&hf[u * S16 + ks * 32 + q * 8];
#pragma unroll
            for (int g = 0; g < 3; ++g)
#pragma unroll
                for (int p = 0; p < 2; ++p)
                    acc[g][p] = __builtin_amdgcn_mfma_f32_16x16x32_f16(
                        afr, bfr[g][p][ks], acc[g][p], 0, 0, 0);
        }
        __syncthreads();  // A reads done before hf is overwritten

        // ============ phase 2: gates + h update + fc partials ============
        const int tN = t * N_;
#pragma unroll
        for (int reg = 0; reg < 4; ++reg) {
            const int lr  = q * 4 + reg;
            const int ob  = obase[reg] + tN;
            const float xp  = xlds[lr];
            const float pmv = pml[t * MROWS + lr];
            float xsum = 0.0f;
#pragma unroll
            for (int p = 0; p < 2; ++p) {
                const int i = (2 * w + p) * 16 + u;
                const float r  = sigm_f(xp * w0[0][p] + pmv * w1[0][p] + acc[0][p][reg] + brz0[p]);
                const float z  = sigm_f(xp * w0[1][p] + pmv * w1[1][p] + acc[1][p][reg] + brz1[p]);
                const float nt = tanh_f(xp * w0[2][p] + pmv * w1[2][p] + bin_[p] +
                                        r * (acc[2][p][reg] + bhn_[p]));
                const float hnew = (1.0f - z) * nt + z * hreg[p][reg];
                hreg[p][reg] = hnew;
                hf[lr * S16 + i] = (_Float16)hnew;
                out[(size_t)ob * H_ + i] = hnew;
                xsum += hnew * fcwr[p];
            }
            // reduce over the 16 u-lanes of this quad
            xsum += __shfl_xor(xsum, 1, 64);
            xsum += __shfl_xor(xsum, 2, 64);
            xsum += __shfl_xor(xsum, 4, 64);
            xsum += __shfl_xor(xsum, 8, 64);
            if (u == 0) xpart[w * MROWS + lr] = xsum;
        }
        __syncthreads();  // xpart ready; hf writes done before next MFMA reads

        // ============ phase 3: finish x_new ============
        if (tid < MROWS) {
            const float x = xpart[tid] + xpart[MROWS + tid] + xpart[2 * MROWS + tid] +
                            xpart[3 * MROWS + tid] + fcbv;
            xlds[tid] = x;
            if (t == T_ - 1) {
                out[(size_t)HSZ + blockIdx.x * MROWS + tid] = x;
            }
        }
        // next phase-1 doesn't touch xlds/xpart; the phase-1-end barrier
        // orders phase-3's xlds write before the next gate phase reads it.
    }
}

extern "C" void kernel_launch(void* const* d_in, const int* in_sizes, int n_in,
                              void* d_out, int out_size, void* d_ws, size_t ws_size,
                              hipStream_t stream) {
    const float* pm  = (const float*)d_in[0];  // [B,T,N,1]
    const float* Wih = (const float*)d_in[1];  // [384,2]
    const float* Whh = (const float*)d_in[2];  // [384,128]
    const float* bih = (const float*)d_in[3];  // [384]
    const float* bhh = (const float*)d_in[4];  // [384]
    const float* fcw = (const float*)d_in[5];  // [1,128]
    const float* fcb = (const float*)d_in[6];  // [1]
    float* out = (float*)d_out;

    gru_encoder_kernel<<<dim3(NBLK), dim3(256), 0, stream>>>(
        pm, Wih, Whh, bih, bhh, fcw, fcb, out);
}

// Round 3
// 203.819 us; speedup vs baseline: 1.7704x; 1.1139x over previous
//
#include <hip/hip_runtime.h>
#include <hip/hip_fp16.h>

// GRU encoder: B=64, T=24, N=184, HID=128, in_dim 2 (prev fc out, pm_t).
// R3: 736 blocks x 512 threads, 16 rows/block. Each wave owns 16 hidden cols
// (8 waves x 16 = 128) -> B-frags only 48 VGPRs/lane, targeting 4 waves/SIMD
// (2 blocks/CU resident). fc layer folded into the recurrence:
//   r,z B-frags = Whh + Wih[:,0] (x) fcw  (rank-1 fold, x_t = fc(h_{t-1}))
//   x_t computed by an extra MFMA whose B has fcw in EVERY column -> each
//   lane holds x[row] directly (no cross-wave reduction, no shfl, no xpart).
// hf (f16 h copy, MFMA A operand) double-buffered -> exactly 1 barrier/step.

#define B_   64
#define T_   24
#define N_   184
#define H_   128
#define BN   (B_ * N_)            // 11776
#define TN   (T_ * N_)            // 4416
#define HSZ  (B_ * T_ * N_ * H_)  // 36175872
#define MROWS 16
#define NBLK  (BN / MROWS)        // 736, exact
#define S16   136                 // f16 h row stride in halves (272B, 16B-aligned)

typedef _Float16 v8h __attribute__((ext_vector_type(8)));
typedef float    v4f __attribute__((ext_vector_type(4)));

static __device__ __forceinline__ float fast_rcp(float x) {
#if __has_builtin(__builtin_amdgcn_rcpf)
    return __builtin_amdgcn_rcpf(x);
#else
    return 1.0f / x;
#endif
}
static __device__ __forceinline__ float sigm_f(float x) {
    return fast_rcp(1.0f + __expf(-x));
}
static __device__ __forceinline__ float tanh_f(float x) {
    return 1.0f - 2.0f * fast_rcp(1.0f + __expf(2.0f * x));
}

__global__ __launch_bounds__(512, 4)
void gru_encoder_kernel(const float* __restrict__ pm,    // [B,T,N]
                        const float* __restrict__ Wih,   // [384,2]
                        const float* __restrict__ Whh,   // [384,128]
                        const float* __restrict__ bih,   // [384]
                        const float* __restrict__ bhh,   // [384]
                        const float* __restrict__ fcw,   // [128]
                        const float* __restrict__ fcb,   // [1]
                        float* __restrict__ out)         // [HSZ] H + [BN] xn
{
    __shared__ _Float16 hf[2][MROWS * S16];  // double-buffered f16 h (A operand)
    __shared__ float    pml[T_ * MROWS];     // preloaded pm [t][row]

    const int tid  = threadIdx.x;
    const int w    = tid >> 6;   // wave 0..7
    const int lane = tid & 63;
    const int u    = lane & 15;  // A-row / C-col selector
    const int q    = lane >> 4;  // quad
    const int i    = w * 16 + u; // this lane's hidden column (0..127)

    // ---- zero hf[0] (read at t=0) ----
    for (int idx = tid; idx < MROWS * S16; idx += 512) hf[0][idx] = (_Float16)0.0f;

    // ---- preload pm for this block's 16 rows, all 24 steps ----
    for (int idx = tid; idx < T_ * MROWS; idx += 512) {
        const int row = idx & (MROWS - 1);
        const int t   = idx >> 4;
        const int g   = blockIdx.x * MROWS + row;
        const int b   = g / N_;
        const int n   = g - b * N_;
        pml[idx] = pm[b * TN + t * N_ + n];
    }

    // ---- B-fragments (once). r,z folded: W* = Whh + Wih[:,0] (x) fcw ----
    // lane holds B[ks*32 + q*8 + j][i]
    v8h bfr[3][4];
#pragma unroll
    for (int g = 0; g < 3; ++g) {
        const int c = g * 128 + i;
        const float fold = (g < 2) ? Wih[c * 2 + 0] : 0.0f;
#pragma unroll
        for (int ks = 0; ks < 4; ++ks) {
            v8h hb;
#pragma unroll
            for (int j = 0; j < 8; ++j) {
                const int k = ks * 32 + q * 8 + j;
                hb[j] = (_Float16)(Whh[c * 128 + k] + fold * fcw[k]);
            }
            bfr[g][ks] = hb;
        }
    }
    // x-projection B: fcw replicated in every column -> acc_x[reg] = x[row]
    v8h bfx[4];
#pragma unroll
    for (int ks = 0; ks < 4; ++ks) {
        v8h hb;
#pragma unroll
        for (int j = 0; j < 8; ++j) hb[j] = (_Float16)fcw[ks * 32 + q * 8 + j];
        bfx[ks] = hb;
    }

    // ---- per-lane constants ----
    const float w1r = Wih[(0 * 128 + i) * 2 + 1];
    const float w1z = Wih[(1 * 128 + i) * 2 + 1];
    const float w1n = Wih[(2 * 128 + i) * 2 + 1];
    const float w0n = Wih[(2 * 128 + i) * 2 + 0];
    const float fcbv = fcb[0];
    const float brz_r0 = bih[0 * 128 + i] + bhh[0 * 128 + i];
    const float brz_z0 = bih[1 * 128 + i] + bhh[1 * 128 + i];
    const float brz_r1 = brz_r0 + Wih[(0 * 128 + i) * 2 + 0] * fcbv;  // + Wih_r0*fcb for t>=1
    const float brz_z1 = brz_z0 + Wih[(1 * 128 + i) * 2 + 0] * fcbv;
    const float bin_ = bih[2 * 128 + i];
    const float bhn_ = bhh[2 * 128 + i];

    // ---- per-lane row output bases (rows q*4+reg) ----
    int obase[4];
#pragma unroll
    for (int reg = 0; reg < 4; ++reg) {
        const int g = blockIdx.x * MROWS + q * 4 + reg;
        const int b = g / N_;
        obase[reg] = b * TN + (g - b * N_);
    }

    v4f hreg = (v4f){0.f, 0.f, 0.f, 0.f};  // fp32 h state (C-fragment layout)

    __syncthreads();

    for (int t = 0; t < T_; ++t) {
        // ===== phase 1: [gh_r*, gh_z*, gh_n, x] = h_{t-1} @ B (MFMA) =====
        const _Float16* hfr = hf[t & 1];
        v4f acc0 = (v4f){0.f, 0.f, 0.f, 0.f};
        v4f acc1 = (v4f){0.f, 0.f, 0.f, 0.f};
        v4f acc2 = (v4f){0.f, 0.f, 0.f, 0.f};
        v4f accx = (v4f){0.f, 0.f, 0.f, 0.f};
#pragma unroll
        for (int ks = 0; ks < 4; ++ks) {
            const v8h afr = *(const v8h*)&hfr[u * S16 + ks * 32 + q * 8];
            acc0 = __builtin_amdgcn_mfma_f32_16x16x32_f16(afr, bfr[0][ks], acc0, 0, 0, 0);
            acc1 = __builtin_amdgcn_mfma_f32_16x16x32_f16(afr, bfr[1][ks], acc1, 0, 0, 0);
            acc2 = __builtin_amdgcn_mfma_f32_16x16x32_f16(afr, bfr[2][ks], acc2, 0, 0, 0);
            accx = __builtin_amdgcn_mfma_f32_16x16x32_f16(afr, bfx[ks],    accx, 0, 0, 0);
        }

        // ===== phase 2: gates + h update + stores =====
        _Float16* hfw = hf[(t + 1) & 1];
        const float brzr = (t == 0) ? brz_r0 : brz_r1;
        const float brzz = (t == 0) ? brz_z0 : brz_z1;
        const int tN = t * N_;
#pragma unroll
        for (int reg = 0; reg < 4; ++reg) {
            const int lr   = q * 4 + reg;
            const float pmv = pml[t * MROWS + lr];
            const float xv  = (t == 0) ? 0.0f : (accx[reg] + fcbv);  // x_t = fc(h_{t-1})
            const float r   = sigm_f(acc0[reg] + pmv * w1r + brzr);
            const float z   = sigm_f(acc1[reg] + pmv * w1z + brzz);
            const float nt  = tanh_f(xv * w0n + pmv * w1n + bin_ + r * (acc2[reg] + bhn_));
            const float hnew = nt + z * (hreg[reg] - nt);
            hreg[reg] = hnew;
            hfw[lr * S16 + i] = (_Float16)hnew;
            out[(size_t)(obase[reg] + tN) * H_ + i] = hnew;
        }
        __syncthreads();  // hfw complete before next step's MFMA reads
    }

    // ===== epilogue: xn = fc(h_{T-1}); h_{T-1} is in hf[T_ & 1] = hf[0] =====
    if (w == 0) {
        v4f accx = (v4f){0.f, 0.f, 0.f, 0.f};
#pragma unroll
        for (int ks = 0; ks < 4; ++ks) {
            const v8h afr = *(const v8h*)&hf[0][u * S16 + ks * 32 + q * 8];
            accx = __builtin_amdgcn_mfma_f32_16x16x32_f16(afr, bfx[ks], accx, 0, 0, 0);
        }
        if (u == 0) {
#pragma unroll
            for (int reg = 0; reg < 4; ++reg)
                out[(size_t)HSZ + blockIdx.x * MROWS + q * 4 + reg] = accx[reg] + fcbv;
        }
    }
}

extern "C" void kernel_launch(void* const* d_in, const int* in_sizes, int n_in,
                              void* d_out, int out_size, void* d_ws, size_t ws_size,
                              hipStream_t stream) {
    const float* pm  = (const float*)d_in[0];  // [B,T,N,1]
    const float* Wih = (const float*)d_in[1];  // [384,2]
    const float* Whh = (const float*)d_in[2];  // [384,128]
    const float* bih = (const float*)d_in[3];  // [384]
    const float* bhh = (const float*)d_in[4];  // [384]
    const float* fcw = (const float*)d_in[5];  // [1,128]
    const float* fcb = (const float*)d_in[6];  // [1]
    float* out = (float*)d_out;

    gru_encoder_kernel<<<dim3(NBLK), dim3(512), 0, stream>>>(
        pm, Wih, Whh, bih, bhh, fcw, fcb, out);
}